// Round 4
// baseline (548.894 us; speedup 1.0000x reference)
//
#include <hip/hip_runtime.h>

#define FEATS 64
#define PSZ   64            // nodes per partition (= one gather block)
#define MAXP  1280          // >= ceil(75000/64)+pad
#define PSCH  4688          // edges per pscatter chunk; 4688*256 = 1,200,128 >= 1.2M
#define PEPT  19            // ceil(PSCH/256)
#define NBMAX 256           // max pscatter blocks / runs per partition
#define CAP   2048          // LDS record-staging capacity (mean 1024, 31-sigma safe)

typedef __attribute__((ext_vector_type(8))) short short8;   // 8 bf16 = 4 VGPRs
typedef __attribute__((ext_vector_type(4))) float floatx4;  // MFMA accumulator

static __device__ __forceinline__ unsigned short f2bf(float f) {
    // round-to-nearest-even fp32 -> bf16 bits (inputs finite)
    const unsigned int u = __float_as_uint(f);
    return (unsigned short)((u + 0x7FFFu + ((u >> 16) & 1u)) >> 16);
}

// ---------------------------------------------------------------------------
// K1 prep: winv = rsqrt(degree); Fs = feature * winv[row] (removes the
// per-edge dependent winv[src] load); block 0 also emits Wt in bf16
// (Wt[n][k] = W[k][n]) so MFMA B-fragments are contiguous 16B loads.
// ---------------------------------------------------------------------------
__global__ __launch_bounds__(256) void prep(const float* __restrict__ degree,
                                            const float* __restrict__ feature,
                                            const float* __restrict__ Wm,
                                            float* __restrict__ winv,
                                            float* __restrict__ Fs,
                                            unsigned short* __restrict__ WtB,
                                            int n_nodes) {
    __shared__ float swv[PSZ];
    const int tid = threadIdx.x;
    const int n0 = blockIdx.x * PSZ;
    const int nn = min(PSZ, n_nodes - n0);
    if (tid < nn) {
        const float w = rsqrtf(degree[n0 + tid]);
        winv[n0 + tid] = w;
        swv[tid] = w;
    }
    __syncthreads();
    const float4* fin = (const float4*)(feature + (size_t)n0 * FEATS);
    float4* fo = (float4*)(Fs + (size_t)n0 * FEATS);
    const int nv = nn * (FEATS / 4);
    for (int i = tid; i < nv; i += 256) {
        const float w = swv[i >> 4];
        float4 v = fin[i];
        v.x *= w; v.y *= w; v.z *= w; v.w *= w;
        fo[i] = v;
    }
    if (blockIdx.x == 0) {
        for (int idx = tid; idx < FEATS * FEATS; idx += 256) {
            const int k = idx >> 6, n = idx & 63;
            WtB[n * FEATS + k] = f2bf(Wm[idx]);   // Wm read coalesced
        }
    }
}

// ---------------------------------------------------------------------------
// K2 pscatter3: block b partition-sorts its PSCH-edge chunk in LDS (LDS
// atomics for rank, block scan for offsets), writes the sorted chunk back to
// slab[b*PSCH ...] fully coalesced, and writes its run-offset row
// runoff[b][0..np] (runoff[b][p] = start of partition p's run inside chunk b).
// ZERO global atomics. Record = src | (dst&63)<<17.
// ---------------------------------------------------------------------------
__global__ __launch_bounds__(256) void pscatter3(const int* __restrict__ src,
                                                 const int* __restrict__ dst,
                                                 int* __restrict__ slab,
                                                 int* __restrict__ runoff,
                                                 int n_edges, int np) {
    __shared__ int cnt[MAXP];        // per-partition count, then exclusive loc
    __shared__ int ssum[256];
    __shared__ int sval[PSCH];
    const int tid = threadIdx.x;
    const int b = blockIdx.x;
    const int estart = b * PSCH;
    const int eend = min(estart + PSCH, n_edges);
    const int mb = eend - estart;

    for (int i = tid; i < np; i += 256) cnt[i] = 0;
    __syncthreads();

    int prk[PEPT];
#pragma unroll
    for (int k = 0; k < PEPT; ++k) {
        const int e = estart + tid + (k << 8);
        prk[k] = -1;
        if (e < eend) {
            const int p = dst[e] >> 6;                 // partition (11 bits)
            const int r = atomicAdd(&cnt[p], 1);       // LDS atomic; r < 8192
            prk[k] = p | (r << 11);
        }
    }
    __syncthreads();

    // block-wide exclusive scan of cnt[0..np): 5 partitions per thread
    int my[5];
    int psum = 0;
    const int p0 = tid * 5;
#pragma unroll
    for (int j = 0; j < 5; ++j) {
        const int p = p0 + j;
        my[j] = psum;
        if (p < np) psum += cnt[p];
    }
    ssum[tid] = psum;
    __syncthreads();
#pragma unroll
    for (int o = 1; o < 256; o <<= 1) {
        const int v = (tid >= o) ? ssum[tid - o] : 0;
        __syncthreads();
        ssum[tid] += v;
        __syncthreads();
    }
    const int tbase = ssum[tid] - psum;
#pragma unroll
    for (int j = 0; j < 5; ++j) {
        const int p = p0 + j;
        if (p < np) cnt[p] = tbase + my[j];            // cnt becomes loc
    }
    __syncthreads();

    // place records sorted by partition
#pragma unroll
    for (int k = 0; k < PEPT; ++k) {
        const int e = estart + tid + (k << 8);
        if (e < eend) {
            const int pr = prk[k];
            const int p = pr & 2047;
            const int r = pr >> 11;
            sval[cnt[p] + r] = (src[e] & 0x1FFFF) | ((dst[e] & 63) << 17);
        }
    }
    __syncthreads();

    // coalesced write-back of the sorted chunk + run-offset row
    int* so = slab + estart;
    for (int i = tid; i < mb; i += 256) so[i] = sval[i];
    int* ro = runoff + (size_t)b * (np + 1);
    for (int i = tid; i <= np; i += 256) ro[i] = (i < np) ? cnt[i] : mb;
}

// ---------------------------------------------------------------------------
// K3 gather_apply2: block = partition p.
//  (a) collect p's records from the 256 block-runs into LDS (coalesced-ish,
//      run table is 1.2 MB and L2-cached),
//  (b) edge-parallel streaming: whole wave per edge, lane = feature column,
//      atomicAdd into sagg[dl*64+lane] (bank=lane%32 -> conflict-free; no
//      per-node latency chains; unroll-8 keeps 8 Fs rows in flight),
//  (c) epilogue: sagg -> bf16 (stride 72 kills MFMA LDS bank conflicts),
//      64x64x64 GEMM via mfma_f32_16x16x32_bf16 (8 MFMA/wave),
//      out = winv[n] * (A @ W) + b.
// ---------------------------------------------------------------------------
__global__ __launch_bounds__(256) void gather_apply2(const int* __restrict__ slab,
                                                     const int* __restrict__ runoff,
                                                     const float* __restrict__ winv,
                                                     const float* __restrict__ Fs,
                                                     const unsigned short* __restrict__ WtB,
                                                     const float* __restrict__ bias,
                                                     float* __restrict__ out,
                                                     int n_nodes, int np, int nbs) {
    __shared__ float sagg[PSZ * FEATS];                 // 16 KB fp32 accumulators
    __shared__ __align__(16) int sunion[2304];          // srec (8KB) then saggb (9.2KB)
    __shared__ int sst[NBMAX], sen[NBMAX];
    __shared__ int ssum[256];
    __shared__ float swinv[PSZ];
    int* srec = sunion;
    unsigned short* saggb = (unsigned short*)sunion;    // [64][72] bf16, after streaming

    const int tid = threadIdx.x;
    const int lane = tid & 63;
    const int wv = tid >> 6;
    const int p = blockIdx.x;
    const int n0 = p * PSZ;
    const int nn = min(PSZ, n_nodes - n0);

    // zero accumulators, stage winv tile
    float4* sz = (float4*)sagg;
    for (int i = tid; i < PSZ * FEATS / 4; i += 256) sz[i] = make_float4(0.f, 0.f, 0.f, 0.f);
    if (tid < PSZ) swinv[tid] = (n0 + tid < n_nodes) ? winv[n0 + tid] : 1.0f;

    // run table: chunk t's records for partition p live at slab[t*PSCH+st..en)
    int st = 0, en = 0;
    if (tid < nbs) {
        const int* ro = runoff + (size_t)tid * (np + 1);
        st = ro[p];
        en = ro[p + 1];
    }
    sst[tid] = st;
    sen[tid] = en;
    const int len = en - st;
    ssum[tid] = len;
    __syncthreads();
#pragma unroll
    for (int o = 1; o < 256; o <<= 1) {
        const int v = (tid >= o) ? ssum[tid - o] : 0;
        __syncthreads();
        ssum[tid] += v;
        __syncthreads();
    }
    const int sexc = ssum[tid] - len;
    const int m = ssum[255];

    if (m <= CAP) {
        // stage this partition's records compactly into LDS
        const int gbase = tid * PSCH + st;
        for (int q = 0; q < len; ++q) srec[sexc + q] = slab[gbase + q];
        __syncthreads();

        // edge-parallel streaming, 8 rows in flight per wave
        const int per = ((m + 31) >> 5) << 3;          // multiple of 8
        const int jb = min(wv * per, m);
        const int je = min(jb + per, m);
        int j = jb;
        const int jea = jb + ((je - jb) & ~7);
        for (; j < jea; j += 8) {
            const int4 ra = *(const int4*)(srec + j);
            const int4 rb = *(const int4*)(srec + j + 4);
            const float v0 = Fs[(size_t)(ra.x & 0x1FFFF) * FEATS + lane];
            const float v1 = Fs[(size_t)(ra.y & 0x1FFFF) * FEATS + lane];
            const float v2 = Fs[(size_t)(ra.z & 0x1FFFF) * FEATS + lane];
            const float v3 = Fs[(size_t)(ra.w & 0x1FFFF) * FEATS + lane];
            const float v4 = Fs[(size_t)(rb.x & 0x1FFFF) * FEATS + lane];
            const float v5 = Fs[(size_t)(rb.y & 0x1FFFF) * FEATS + lane];
            const float v6 = Fs[(size_t)(rb.z & 0x1FFFF) * FEATS + lane];
            const float v7 = Fs[(size_t)(rb.w & 0x1FFFF) * FEATS + lane];
            atomicAdd(&sagg[((ra.x >> 17) & 63) * FEATS + lane], v0);
            atomicAdd(&sagg[((ra.y >> 17) & 63) * FEATS + lane], v1);
            atomicAdd(&sagg[((ra.z >> 17) & 63) * FEATS + lane], v2);
            atomicAdd(&sagg[((ra.w >> 17) & 63) * FEATS + lane], v3);
            atomicAdd(&sagg[((rb.x >> 17) & 63) * FEATS + lane], v4);
            atomicAdd(&sagg[((rb.y >> 17) & 63) * FEATS + lane], v5);
            atomicAdd(&sagg[((rb.z >> 17) & 63) * FEATS + lane], v6);
            atomicAdd(&sagg[((rb.w >> 17) & 63) * FEATS + lane], v7);
        }
        for (; j < je; ++j) {
            const int r = srec[j];
            const float v = Fs[(size_t)(r & 0x1FFFF) * FEATS + lane];
            atomicAdd(&sagg[((r >> 17) & 63) * FEATS + lane], v);
        }
        __syncthreads();
    } else {
        // statistically-unreachable overflow: stream runs straight from global
        __syncthreads();
        for (int t = 0; t < nbs; ++t) {
            const int s0 = sst[t], e0 = sen[t];
            const int gb = t * PSCH;
            for (int i = s0 + wv; i < e0; i += 4) {
                const int r = slab[gb + i];
                const float v = Fs[(size_t)(r & 0x1FFFF) * FEATS + lane];
                atomicAdd(&sagg[((r >> 17) & 63) * FEATS + lane], v);
            }
        }
        __syncthreads();
    }

    // convert accumulators to bf16, stride 72 (pad -> conflict-free A-frags)
    for (int idx = tid; idx < PSZ * FEATS / 4; idx += 256) {
        const int row = idx >> 4;
        const int c4 = (idx & 15) << 2;
        const float4 v = ((const float4*)sagg)[idx];
        unsigned int lo = (unsigned int)f2bf(v.x) | ((unsigned int)f2bf(v.y) << 16);
        unsigned int hi = (unsigned int)f2bf(v.z) | ((unsigned int)f2bf(v.w) << 16);
        unsigned int* dp = (unsigned int*)(saggb + row * 72 + c4);
        dp[0] = lo;
        dp[1] = hi;
    }
    __syncthreads();

    // 64x64 (A, LDS bf16) x 64x64 (W, global bf16 transposed): wave wv owns
    // m-tile wv; 4 n-tiles x 2 k-steps = 8 MFMA.
    const int col = lane & 15;
    const int quad = lane >> 4;
    floatx4 acc[4] = {};
#pragma unroll
    for (int kt = 0; kt < 2; ++kt) {
        const short8 af = *(const short8*)(saggb + (wv * 16 + col) * 72 + kt * 32 + quad * 8);
#pragma unroll
        for (int nt = 0; nt < 4; ++nt) {
            const short8 bf = *(const short8*)((const short*)WtB + (nt * 16 + col) * FEATS + kt * 32 + quad * 8);
            acc[nt] = __builtin_amdgcn_mfma_f32_16x16x32_bf16(af, bf, acc[nt], 0, 0, 0);
        }
    }
#pragma unroll
    for (int nt = 0; nt < 4; ++nt) {
        const float bv = bias[nt * 16 + col];
#pragma unroll
        for (int r = 0; r < 4; ++r) {
            const int row = wv * 16 + quad * 4 + r;      // D: col=lane&15, row=quad*4+reg
            if (row < nn)
                out[(size_t)(n0 + row) * FEATS + nt * 16 + col] = swinv[row] * acc[nt][r] + bv;
        }
    }
}

static inline size_t align256(size_t x) { return (x + 255) & ~(size_t)255; }

extern "C" void kernel_launch(void* const* d_in, const int* in_sizes, int n_in,
                              void* d_out, int out_size, void* d_ws, size_t ws_size,
                              hipStream_t stream) {
    const float* feature = (const float*)d_in[0];
    const float* degree  = (const float*)d_in[1];
    const int*   src     = (const int*)d_in[2];
    const int*   dst     = (const int*)d_in[3];
    const float* Wm      = (const float*)d_in[4];
    const float* bias    = (const float*)d_in[5];
    float* out = (float*)d_out;

    const int n_nodes = in_sizes[1];
    const int n_edges = in_sizes[2];
    const int np = (n_nodes + PSZ - 1) / PSZ;           // 1172
    const int nbs = (n_edges + PSCH - 1) / PSCH;        // 256

    // workspace (~25.5 MB), every byte rewritten each launch (no memset needed)
    char* ws = (char*)d_ws;
    float* winv = (float*)ws;            ws += align256((size_t)n_nodes * 4);
    float* Fs   = (float*)ws;            ws += align256((size_t)n_nodes * FEATS * 4);
    unsigned short* WtB = (unsigned short*)ws; ws += align256((size_t)FEATS * FEATS * 2);
    int* slab   = (int*)ws;              ws += align256((size_t)nbs * PSCH * 4);
    int* runoff = (int*)ws;              ws += align256((size_t)nbs * (np + 1) * 4);

    prep<<<np, 256, 0, stream>>>(degree, feature, Wm, winv, Fs, WtB, n_nodes);
    pscatter3<<<nbs, 256, 0, stream>>>(src, dst, slab, runoff, n_edges, np);
    gather_apply2<<<np, 256, 0, stream>>>(slab, runoff, winv, Fs, WtB, bias, out,
                                          n_nodes, np, nbs);
}

// Round 5
// 542.483 us; speedup vs baseline: 1.0118x; 1.0118x over previous
//
#include <hip/hip_runtime.h>

#define FEATS 64
#define PSZ   64            // nodes per partition (= one gather block)
#define MAXP  1280          // >= ceil(75000/64) = 1172
#define PSCH  2344          // edges per pscatter chunk; 2344*512 >= 1.2M
#define PEPT  10            // ceil(PSCH/256)
#define NBMAX 512           // pscatter blocks = runs per partition
#define CAP   2048          // LDS record-staging capacity (mean 1024, 32-sigma)

typedef __attribute__((ext_vector_type(8))) short short8;   // 8 bf16 = 4 VGPRs
typedef __attribute__((ext_vector_type(4))) float floatx4;  // MFMA accumulator

static __device__ __forceinline__ unsigned short f2bf(float f) {
    const unsigned int u = __float_as_uint(f);
    return (unsigned short)((u + 0x7FFFu + ((u >> 16) & 1u)) >> 16);
}

// ---------------------------------------------------------------------------
// K1 prep: winv = rsqrt(degree); Fs = feature * winv[row]; block 0 emits
// W transposed in bf16 for contiguous MFMA B-fragments.
// ---------------------------------------------------------------------------
__global__ __launch_bounds__(256) void prep(const float* __restrict__ degree,
                                            const float* __restrict__ feature,
                                            const float* __restrict__ Wm,
                                            float* __restrict__ winv,
                                            float* __restrict__ Fs,
                                            unsigned short* __restrict__ WtB,
                                            int n_nodes) {
    __shared__ float swv[PSZ];
    const int tid = threadIdx.x;
    const int n0 = blockIdx.x * PSZ;
    const int nn = min(PSZ, n_nodes - n0);
    if (tid < nn) {
        const float w = rsqrtf(degree[n0 + tid]);
        winv[n0 + tid] = w;
        swv[tid] = w;
    }
    __syncthreads();
    const float4* fin = (const float4*)(feature + (size_t)n0 * FEATS);
    float4* fo = (float4*)(Fs + (size_t)n0 * FEATS);
    const int nv = nn * (FEATS / 4);
    for (int i = tid; i < nv; i += 256) {
        const float w = swv[i >> 4];
        float4 v = fin[i];
        v.x *= w; v.y *= w; v.z *= w; v.w *= w;
        fo[i] = v;
    }
    if (blockIdx.x == 0) {
        for (int idx = tid; idx < FEATS * FEATS; idx += 256) {
            const int k = idx >> 6, n = idx & 63;
            WtB[n * FEATS + k] = f2bf(Wm[idx]);
        }
    }
}

// ---------------------------------------------------------------------------
// K2 pscatter3: block b partition-sorts its PSCH-edge chunk in LDS (int LDS
// atomics = native), writes the sorted chunk back coalesced, plus a u16
// run-offset row. ZERO global atomics. 512 blocks -> 2 blocks/CU.
// Record = src | dl<<17 ; prk = p | r<<11 | dl<<23.
// ---------------------------------------------------------------------------
__global__ __launch_bounds__(256) void pscatter3(const int* __restrict__ src,
                                                 const int* __restrict__ dst,
                                                 int* __restrict__ slab,
                                                 unsigned short* __restrict__ runoff,
                                                 int n_edges, int np) {
    __shared__ int cnt[MAXP];        // per-partition count, then exclusive loc
    __shared__ int ssum[256];
    __shared__ int sval[PSCH];
    const int tid = threadIdx.x;
    const int b = blockIdx.x;
    const int estart = b * PSCH;
    const int eend = min(estart + PSCH, n_edges);
    const int mb = eend - estart;

    for (int i = tid; i < np; i += 256) cnt[i] = 0;
    __syncthreads();

    int prk[PEPT];
#pragma unroll
    for (int k = 0; k < PEPT; ++k) {
        const int e = estart + tid + (k << 8);
        prk[k] = 0;
        if (e < eend) {
            const int d = dst[e];
            const int p = d >> 6;                      // 11 bits
            const int r = atomicAdd(&cnt[p], 1);       // LDS atomic (native int)
            prk[k] = p | (r << 11) | ((d & 63) << 23); // r < 2344 (12 bits)
        }
    }
    __syncthreads();

    // block-wide exclusive scan of cnt[0..np): 5 partitions per thread
    int my[5];
    int psum = 0;
    const int p0 = tid * 5;
#pragma unroll
    for (int j = 0; j < 5; ++j) {
        const int p = p0 + j;
        my[j] = psum;
        if (p < np) psum += cnt[p];
    }
    ssum[tid] = psum;
    __syncthreads();
#pragma unroll
    for (int o = 1; o < 256; o <<= 1) {
        const int v = (tid >= o) ? ssum[tid - o] : 0;
        __syncthreads();
        ssum[tid] += v;
        __syncthreads();
    }
    const int tbase = ssum[tid] - psum;
#pragma unroll
    for (int j = 0; j < 5; ++j) {
        const int p = p0 + j;
        if (p < np) cnt[p] = tbase + my[j];            // cnt becomes loc
    }
    __syncthreads();

    // place records sorted by partition (reload only src; dl is in prk)
#pragma unroll
    for (int k = 0; k < PEPT; ++k) {
        const int e = estart + tid + (k << 8);
        if (e < eend) {
            const int pr = prk[k];
            const int p = pr & 2047;
            const int r = (pr >> 11) & 4095;
            const int dl = (pr >> 23) & 63;
            sval[cnt[p] + r] = (src[e] & 0x1FFFF) | (dl << 17);
        }
    }
    __syncthreads();

    int* so = slab + estart;
    for (int i = tid; i < mb; i += 256) so[i] = sval[i];   // coalesced
    unsigned short* ro = runoff + (size_t)b * (np + 1);
    for (int i = tid; i <= np; i += 256)
        ro[i] = (unsigned short)((i < np) ? cnt[i] : mb);
}

// ---------------------------------------------------------------------------
// K3 gather_apply2: block = partition p.
//  (a) stage p's records from the 512 chunk-runs into LDS,
//  (b) edge-parallel streaming: wave per edge, lane = feature column,
//      unsafeAtomicAdd -> native no-return ds fp32 add (NO CAS loop, no
//      latency chain); 8 Fs rows in flight per wave,
//  (c) epilogue: sagg -> bf16 (stride 72), 64x64x64 GEMM via
//      mfma_f32_16x16x32_bf16, out = winv[n]*(A@W)+b.
// ---------------------------------------------------------------------------
__global__ __launch_bounds__(256) void gather_apply2(const int* __restrict__ slab,
                                                     const unsigned short* __restrict__ runoff,
                                                     const float* __restrict__ winv,
                                                     const float* __restrict__ Fs,
                                                     const unsigned short* __restrict__ WtB,
                                                     const float* __restrict__ bias,
                                                     float* __restrict__ out,
                                                     int n_nodes, int np, int nbs) {
    __shared__ float sagg[PSZ * FEATS];                 // 16 KB fp32 accumulators
    __shared__ __align__(16) int sunion[2304];          // srec (8KB) then saggb (9.2KB)
    __shared__ int sst[NBMAX], sen[NBMAX];
    __shared__ int ssum[256];
    __shared__ float swinv[PSZ];
    int* srec = sunion;
    unsigned short* saggb = (unsigned short*)sunion;    // [64][72] bf16, post-streaming

    const int tid = threadIdx.x;
    const int lane = tid & 63;
    const int wv = tid >> 6;
    const int p = blockIdx.x;
    const int n0 = p * PSZ;
    const int nn = min(PSZ, n_nodes - n0);

    float4* sz = (float4*)sagg;
    for (int i = tid; i < PSZ * FEATS / 4; i += 256) sz[i] = make_float4(0.f, 0.f, 0.f, 0.f);
    if (tid < PSZ) swinv[tid] = (n0 + tid < n_nodes) ? winv[n0 + tid] : 1.0f;

    // run table: thread t owns runs t and t+256
    int st0 = 0, l0 = 0, st1 = 0, l1 = 0;
    {
        const unsigned short* ro = runoff + (size_t)tid * (np + 1);
        st0 = ro[p];
        l0 = (int)ro[p + 1] - st0;
    }
    if (tid + 256 < nbs) {
        const unsigned short* ro = runoff + (size_t)(tid + 256) * (np + 1);
        st1 = ro[p];
        l1 = (int)ro[p + 1] - st1;
    }
    sst[tid] = st0;        sen[tid] = st0 + l0;
    sst[tid + 256] = st1;  sen[tid + 256] = st1 + l1;
    const int lt = l0 + l1;
    ssum[tid] = lt;
    __syncthreads();
#pragma unroll
    for (int o = 1; o < 256; o <<= 1) {
        const int v = (tid >= o) ? ssum[tid - o] : 0;
        __syncthreads();
        ssum[tid] += v;
        __syncthreads();
    }
    const int base = ssum[tid] - lt;
    const int m = ssum[255];

    if (m <= CAP) {
        // stage records compactly into LDS
        const int* g0 = slab + (size_t)tid * PSCH;
        for (int q = 0; q < l0; ++q) srec[base + q] = g0[st0 + q];
        if (l1 > 0) {
            const int* g1 = slab + (size_t)(tid + 256) * PSCH;
            for (int q = 0; q < l1; ++q) srec[base + l0 + q] = g1[st1 + q];
        }
        __syncthreads();

        // edge-parallel streaming, native fp32 LDS adds, 8 rows in flight
        const int per = ((m + 31) >> 5) << 3;          // ~m/4, multiple of 8
        const int jb = min(wv * per, m);
        const int je = min(jb + per, m);
        int j = jb;
        const int jea = jb + ((je - jb) & ~7);
        for (; j < jea; j += 8) {
            const int4 ra = *(const int4*)(srec + j);
            const int4 rb = *(const int4*)(srec + j + 4);
            const float v0 = Fs[(size_t)(ra.x & 0x1FFFF) * FEATS + lane];
            const float v1 = Fs[(size_t)(ra.y & 0x1FFFF) * FEATS + lane];
            const float v2 = Fs[(size_t)(ra.z & 0x1FFFF) * FEATS + lane];
            const float v3 = Fs[(size_t)(ra.w & 0x1FFFF) * FEATS + lane];
            const float v4 = Fs[(size_t)(rb.x & 0x1FFFF) * FEATS + lane];
            const float v5 = Fs[(size_t)(rb.y & 0x1FFFF) * FEATS + lane];
            const float v6 = Fs[(size_t)(rb.z & 0x1FFFF) * FEATS + lane];
            const float v7 = Fs[(size_t)(rb.w & 0x1FFFF) * FEATS + lane];
            unsafeAtomicAdd(&sagg[((ra.x >> 17) & 63) * FEATS + lane], v0);
            unsafeAtomicAdd(&sagg[((ra.y >> 17) & 63) * FEATS + lane], v1);
            unsafeAtomicAdd(&sagg[((ra.z >> 17) & 63) * FEATS + lane], v2);
            unsafeAtomicAdd(&sagg[((ra.w >> 17) & 63) * FEATS + lane], v3);
            unsafeAtomicAdd(&sagg[((rb.x >> 17) & 63) * FEATS + lane], v4);
            unsafeAtomicAdd(&sagg[((rb.y >> 17) & 63) * FEATS + lane], v5);
            unsafeAtomicAdd(&sagg[((rb.z >> 17) & 63) * FEATS + lane], v6);
            unsafeAtomicAdd(&sagg[((rb.w >> 17) & 63) * FEATS + lane], v7);
        }
        for (; j < je; ++j) {
            const int r = srec[j];
            unsafeAtomicAdd(&sagg[((r >> 17) & 63) * FEATS + lane],
                            Fs[(size_t)(r & 0x1FFFF) * FEATS + lane]);
        }
        __syncthreads();
    } else {
        // statistically-unreachable overflow: stream runs straight from global
        __syncthreads();
        for (int t = wv; t < nbs; t += 4) {
            const int gb = t * PSCH;
            const int s0 = sst[t], e0 = sen[t];
            for (int i = s0; i < e0; ++i) {
                const int r = slab[gb + i];
                unsafeAtomicAdd(&sagg[((r >> 17) & 63) * FEATS + lane],
                                Fs[(size_t)(r & 0x1FFFF) * FEATS + lane]);
            }
        }
        __syncthreads();
    }

    // accumulators -> bf16, stride 72 (conflict-free MFMA A-frags)
    for (int idx = tid; idx < PSZ * FEATS / 4; idx += 256) {
        const int row = idx >> 4;
        const int c4 = (idx & 15) << 2;
        const float4 v = ((const float4*)sagg)[idx];
        unsigned int lo = (unsigned int)f2bf(v.x) | ((unsigned int)f2bf(v.y) << 16);
        unsigned int hi = (unsigned int)f2bf(v.z) | ((unsigned int)f2bf(v.w) << 16);
        unsigned int* dp = (unsigned int*)(saggb + row * 72 + c4);
        dp[0] = lo;
        dp[1] = hi;
    }
    __syncthreads();

    // 64x64x64 GEMM: wave wv owns m-tile wv; 4 n-tiles x 2 k-steps = 8 MFMA
    const int col = lane & 15;
    const int quad = lane >> 4;
    floatx4 acc[4] = {};
#pragma unroll
    for (int kt = 0; kt < 2; ++kt) {
        const short8 af = *(const short8*)(saggb + (wv * 16 + col) * 72 + kt * 32 + quad * 8);
#pragma unroll
        for (int nt = 0; nt < 4; ++nt) {
            const short8 bf = *(const short8*)((const short*)WtB + (nt * 16 + col) * FEATS + kt * 32 + quad * 8);
            acc[nt] = __builtin_amdgcn_mfma_f32_16x16x32_bf16(af, bf, acc[nt], 0, 0, 0);
        }
    }
#pragma unroll
    for (int nt = 0; nt < 4; ++nt) {
        const float bv = bias[nt * 16 + col];
#pragma unroll
        for (int r = 0; r < 4; ++r) {
            const int row = wv * 16 + quad * 4 + r;      // D: col=lane&15, row=quad*4+reg
            if (row < nn)
                out[(size_t)(n0 + row) * FEATS + nt * 16 + col] = swinv[row] * acc[nt][r] + bv;
        }
    }
}

static inline size_t align256(size_t x) { return (x + 255) & ~(size_t)255; }

extern "C" void kernel_launch(void* const* d_in, const int* in_sizes, int n_in,
                              void* d_out, int out_size, void* d_ws, size_t ws_size,
                              hipStream_t stream) {
    const float* feature = (const float*)d_in[0];
    const float* degree  = (const float*)d_in[1];
    const int*   src     = (const int*)d_in[2];
    const int*   dst     = (const int*)d_in[3];
    const float* Wm      = (const float*)d_in[4];
    const float* bias    = (const float*)d_in[5];
    float* out = (float*)d_out;

    const int n_nodes = in_sizes[1];
    const int n_edges = in_sizes[2];
    const int np = (n_nodes + PSZ - 1) / PSZ;           // 1172
    const int nbs = (n_edges + PSCH - 1) / PSCH;        // 512

    // workspace (~25.5 MB), every byte rewritten each launch
    char* ws = (char*)d_ws;
    float* winv = (float*)ws;                  ws += align256((size_t)n_nodes * 4);
    float* Fs   = (float*)ws;                  ws += align256((size_t)n_nodes * FEATS * 4);
    unsigned short* WtB = (unsigned short*)ws; ws += align256((size_t)FEATS * FEATS * 2);
    int* slab   = (int*)ws;                    ws += align256((size_t)nbs * PSCH * 4);
    unsigned short* runoff = (unsigned short*)ws; ws += align256((size_t)nbs * (np + 1) * 2);

    prep<<<np, 256, 0, stream>>>(degree, feature, Wm, winv, Fs, WtB, n_nodes);
    pscatter3<<<nbs, 256, 0, stream>>>(src, dst, slab, runoff, n_edges, np);
    gather_apply2<<<np, 256, 0, stream>>>(slab, runoff, winv, Fs, WtB, bias, out,
                                          n_nodes, np, nbs);
}

// Round 6
// 152.243 us; speedup vs baseline: 3.6054x; 3.5633x over previous
//
#include <hip/hip_runtime.h>

#define FEATS 64
#define PSZ   64            // nodes per partition (= one gather block)
#define MAXP  1280          // >= ceil(75000/64) = 1172
#define PSCH  2344          // edges per pscatter chunk; 2344*512 >= 1.2M
#define PEPT  10            // ceil(PSCH/256)
#define NBMAX 512           // pscatter blocks = runs per partition
#define CAPP  2560          // padded LDS bucket capacity (mean ~1030, >30 sigma)

typedef __attribute__((ext_vector_type(8))) short short8;   // 8 bf16 = 4 VGPRs
typedef __attribute__((ext_vector_type(4))) float floatx4;  // MFMA accumulator

static __device__ __forceinline__ unsigned short f2bf(float f) {
    const unsigned int u = __float_as_uint(f);
    return (unsigned short)((u + 0x7FFFu + ((u >> 16) & 1u)) >> 16);
}

// ---------------------------------------------------------------------------
// K1 prep: winv = rsqrt(degree); Fs = feature * winv[row]; block 0 emits
// W transposed in bf16 for contiguous MFMA B-fragments.
// ---------------------------------------------------------------------------
__global__ __launch_bounds__(256) void prep(const float* __restrict__ degree,
                                            const float* __restrict__ feature,
                                            const float* __restrict__ Wm,
                                            float* __restrict__ winv,
                                            float* __restrict__ Fs,
                                            unsigned short* __restrict__ WtB,
                                            int n_nodes) {
    __shared__ float swv[PSZ];
    const int tid = threadIdx.x;
    const int n0 = blockIdx.x * PSZ;
    const int nn = min(PSZ, n_nodes - n0);
    if (tid < nn) {
        const float w = rsqrtf(degree[n0 + tid]);
        winv[n0 + tid] = w;
        swv[tid] = w;
    }
    __syncthreads();
    const float4* fin = (const float4*)(feature + (size_t)n0 * FEATS);
    float4* fo = (float4*)(Fs + (size_t)n0 * FEATS);
    const int nv = nn * (FEATS / 4);
    for (int i = tid; i < nv; i += 256) {
        const float w = swv[i >> 4];
        float4 v = fin[i];
        v.x *= w; v.y *= w; v.z *= w; v.w *= w;
        fo[i] = v;
    }
    if (blockIdx.x == 0) {
        for (int idx = tid; idx < FEATS * FEATS; idx += 256) {
            const int k = idx >> 6, n = idx & 63;
            WtB[n * FEATS + k] = f2bf(Wm[idx]);
        }
    }
}

// ---------------------------------------------------------------------------
// K2 pscatter3: block b partition-sorts its PSCH-edge chunk in LDS (native
// int LDS atomics), writes the sorted chunk back coalesced + a u16 run-offset
// row. ZERO global atomics. Record = src | dl<<17 ; prk = p | r<<11 | dl<<23.
// ---------------------------------------------------------------------------
__global__ __launch_bounds__(256) void pscatter3(const int* __restrict__ src,
                                                 const int* __restrict__ dst,
                                                 int* __restrict__ slab,
                                                 unsigned short* __restrict__ runoff,
                                                 int n_edges, int np) {
    __shared__ int cnt[MAXP];        // per-partition count, then exclusive loc
    __shared__ int ssum[256];
    __shared__ int sval[PSCH];
    const int tid = threadIdx.x;
    const int b = blockIdx.x;
    const int estart = b * PSCH;
    const int eend = min(estart + PSCH, n_edges);
    const int mb = eend - estart;

    for (int i = tid; i < np; i += 256) cnt[i] = 0;
    __syncthreads();

    int prk[PEPT];
#pragma unroll
    for (int k = 0; k < PEPT; ++k) {
        const int e = estart + tid + (k << 8);
        prk[k] = 0;
        if (e < eend) {
            const int d = dst[e];
            const int p = d >> 6;                      // 11 bits
            const int r = atomicAdd(&cnt[p], 1);       // LDS atomic (native int)
            prk[k] = p | (r << 11) | ((d & 63) << 23); // r < 2344 (12 bits)
        }
    }
    __syncthreads();

    // block-wide exclusive scan of cnt[0..np): 5 partitions per thread
    int my[5];
    int psum = 0;
    const int p0 = tid * 5;
#pragma unroll
    for (int j = 0; j < 5; ++j) {
        const int p = p0 + j;
        my[j] = psum;
        if (p < np) psum += cnt[p];
    }
    ssum[tid] = psum;
    __syncthreads();
#pragma unroll
    for (int o = 1; o < 256; o <<= 1) {
        const int v = (tid >= o) ? ssum[tid - o] : 0;
        __syncthreads();
        ssum[tid] += v;
        __syncthreads();
    }
    const int tbase = ssum[tid] - psum;
#pragma unroll
    for (int j = 0; j < 5; ++j) {
        const int p = p0 + j;
        if (p < np) cnt[p] = tbase + my[j];            // cnt becomes loc
    }
    __syncthreads();

#pragma unroll
    for (int k = 0; k < PEPT; ++k) {
        const int e = estart + tid + (k << 8);
        if (e < eend) {
            const int pr = prk[k];
            const int p = pr & 2047;
            const int r = (pr >> 11) & 4095;
            const int dl = (pr >> 23) & 63;
            sval[cnt[p] + r] = (src[e] & 0x1FFFF) | (dl << 17);
        }
    }
    __syncthreads();

    int* so = slab + estart;
    for (int i = tid; i < mb; i += 256) so[i] = sval[i];   // coalesced
    unsigned short* ro = runoff + (size_t)b * (np + 1);
    for (int i = tid; i <= np; i += 256)
        ro[i] = (unsigned short)((i < np) ? cnt[i] : mb);
}

// ---------------------------------------------------------------------------
// K3 gather_apply3: block = partition p. NO fp32 LDS atomics.
//  (a) per-node exclusive offsets (8-aligned) from degree, via wave-0 scan,
//  (b) bucket records by node straight from the sorted slab runs into ledges
//      (int LDS atomic rank only — ~73 wave-ops/CU total),
//  (c) per-node REGISTER accumulation: wave per node, 4 acc chains, 8 Fs
//      rows in flight (aligned int4 broadcast reads of the edge list),
//  (d) MFMA epilogue: rows -> bf16 LDS (stride 72), 8x mfma_16x16x32_bf16,
//      out = winv[n]*(A@W)+b.
// ---------------------------------------------------------------------------
__global__ __launch_bounds__(256) void gather_apply3(const int* __restrict__ slab,
                                                     const unsigned short* __restrict__ runoff,
                                                     const float* __restrict__ degree,
                                                     const float* __restrict__ winv,
                                                     const float* __restrict__ Fs,
                                                     const unsigned short* __restrict__ WtB,
                                                     const float* __restrict__ bias,
                                                     float* __restrict__ out,
                                                     int n_nodes, int np, int nbs) {
    __shared__ __align__(16) int ledges[CAPP];          // 10 KB (fallback: run st/en)
    __shared__ __align__(16) unsigned short saggb[PSZ * 72];  // 9.2 KB bf16 A-tile
    __shared__ int boffA[PSZ + 1];                      // 8-aligned bucket starts
    __shared__ int bcnt[PSZ];                           // raw per-node counts
    __shared__ int bcur[PSZ];
    __shared__ float swinv[PSZ];

    const int tid = threadIdx.x;
    const int lane = tid & 63;
    const int wv = tid >> 6;
    const int p = blockIdx.x;
    const int n0 = p * PSZ;
    const int nn = min(PSZ, n_nodes - n0);

    if (tid < PSZ) {
        bcur[tid] = 0;
        swinv[tid] = (n0 + tid < n_nodes) ? winv[n0 + tid] : 1.0f;
    }
    if (wv == 0) {   // wave-0 shuffle scan of padded per-node counts
        const int c = (lane < nn) ? ((int)(degree[n0 + lane] + 0.5f) - 1) : 0;
        const int cp = (c + 7) & ~7;
        int x = cp;
#pragma unroll
        for (int off = 1; off < 64; off <<= 1) {
            const int v = __shfl_up(x, off);
            if (lane >= off) x += v;
        }
        if (lane == 0) boffA[0] = 0;
        boffA[lane + 1] = x;                 // inclusive scan of padded counts
        bcnt[lane] = c;
    }
    __syncthreads();
    const int mpad = boffA[PSZ];

    if (mpad <= CAPP) {
        // (b) bucket straight from global: thread t walks runs t and t+256
        for (int rr = tid; rr < nbs; rr += 256) {
            const unsigned short* ro = runoff + (size_t)rr * (np + 1);
            const int st = ro[p];
            const int en = ro[p + 1];
            const int* g = slab + (size_t)rr * PSCH;
            for (int q = st; q < en; ++q) {
                const int rec = g[q];
                const int dl = (rec >> 17) & 63;
                const int pos = boffA[dl] + atomicAdd(&bcur[dl], 1);
                ledges[pos] = rec & 0x1FFFF;
            }
        }
        __syncthreads();

        // (c) per-node register accumulation, 8 loads in flight
        for (int n = wv; n < PSZ; n += 4) {
            const int st = boffA[n];
            const int en = st + bcnt[n];
            float a0 = 0.f, a1 = 0.f, a2 = 0.f, a3 = 0.f;
            int j = st;
            for (; j + 8 <= en; j += 8) {
                const int4 ra = *(const int4*)(ledges + j);       // 16B-aligned
                const int4 rb = *(const int4*)(ledges + j + 4);
                a0 += Fs[((size_t)ra.x << 6) + lane];
                a1 += Fs[((size_t)ra.y << 6) + lane];
                a2 += Fs[((size_t)ra.z << 6) + lane];
                a3 += Fs[((size_t)ra.w << 6) + lane];
                a0 += Fs[((size_t)rb.x << 6) + lane];
                a1 += Fs[((size_t)rb.y << 6) + lane];
                a2 += Fs[((size_t)rb.z << 6) + lane];
                a3 += Fs[((size_t)rb.w << 6) + lane];
            }
            if (j + 4 <= en) {
                const int4 ra = *(const int4*)(ledges + j);
                a0 += Fs[((size_t)ra.x << 6) + lane];
                a1 += Fs[((size_t)ra.y << 6) + lane];
                a2 += Fs[((size_t)ra.z << 6) + lane];
                a3 += Fs[((size_t)ra.w << 6) + lane];
                j += 4;
            }
            for (; j < en; ++j)
                a0 += Fs[((size_t)ledges[j] << 6) + lane];
            saggb[n * 72 + lane] = f2bf((a0 + a1) + (a2 + a3));
        }
    } else {
        // statistically-unreachable overflow: reuse ledges for run bounds,
        // then per-node scan of all runs (O(m*16), correctness-only path)
        for (int rr = tid; rr < nbs; rr += 256) {
            const unsigned short* ro = runoff + (size_t)rr * (np + 1);
            ledges[rr] = ro[p];
            ledges[NBMAX + rr] = ro[p + 1];
        }
        __syncthreads();
        for (int n = wv; n < PSZ; n += 4) {
            float acc = 0.f;
            for (int t = 0; t < nbs; ++t) {
                const int gb = t * PSCH;
                const int e0 = ledges[NBMAX + t];
                for (int i = ledges[t]; i < e0; ++i) {
                    const int rec = slab[gb + i];
                    if (((rec >> 17) & 63) == n)
                        acc += Fs[((size_t)(rec & 0x1FFFF) << 6) + lane];
                }
            }
            saggb[n * 72 + lane] = f2bf(acc);
        }
    }
    __syncthreads();

    // (d) 64x64x64 GEMM: wave wv owns m-tile wv; 4 n-tiles x 2 k-steps = 8 MFMA
    const int col = lane & 15;
    const int quad = lane >> 4;
    floatx4 acc[4] = {};
#pragma unroll
    for (int kt = 0; kt < 2; ++kt) {
        const short8 af = *(const short8*)(saggb + (wv * 16 + col) * 72 + kt * 32 + quad * 8);
#pragma unroll
        for (int nt = 0; nt < 4; ++nt) {
            const short8 bf = *(const short8*)((const short*)WtB + (nt * 16 + col) * FEATS + kt * 32 + quad * 8);
            acc[nt] = __builtin_amdgcn_mfma_f32_16x16x32_bf16(af, bf, acc[nt], 0, 0, 0);
        }
    }
#pragma unroll
    for (int nt = 0; nt < 4; ++nt) {
        const float bv = bias[nt * 16 + col];
#pragma unroll
        for (int r = 0; r < 4; ++r) {
            const int row = wv * 16 + quad * 4 + r;      // D: col=lane&15, row=quad*4+reg
            if (row < nn)
                out[(size_t)(n0 + row) * FEATS + nt * 16 + col] = swinv[row] * acc[nt][r] + bv;
        }
    }
}

static inline size_t align256(size_t x) { return (x + 255) & ~(size_t)255; }

extern "C" void kernel_launch(void* const* d_in, const int* in_sizes, int n_in,
                              void* d_out, int out_size, void* d_ws, size_t ws_size,
                              hipStream_t stream) {
    const float* feature = (const float*)d_in[0];
    const float* degree  = (const float*)d_in[1];
    const int*   src     = (const int*)d_in[2];
    const int*   dst     = (const int*)d_in[3];
    const float* Wm      = (const float*)d_in[4];
    const float* bias    = (const float*)d_in[5];
    float* out = (float*)d_out;

    const int n_nodes = in_sizes[1];
    const int n_edges = in_sizes[2];
    const int np = (n_nodes + PSZ - 1) / PSZ;           // 1172
    const int nbs = (n_edges + PSCH - 1) / PSCH;        // 512

    // workspace (~25.5 MB), every byte read is rewritten each launch
    char* ws = (char*)d_ws;
    float* winv = (float*)ws;                  ws += align256((size_t)n_nodes * 4);
    float* Fs   = (float*)ws;                  ws += align256((size_t)n_nodes * FEATS * 4);
    unsigned short* WtB = (unsigned short*)ws; ws += align256((size_t)FEATS * FEATS * 2);
    int* slab   = (int*)ws;                    ws += align256((size_t)nbs * PSCH * 4);
    unsigned short* runoff = (unsigned short*)ws; ws += align256((size_t)nbs * (np + 1) * 2);

    prep<<<np, 256, 0, stream>>>(degree, feature, Wm, winv, Fs, WtB, n_nodes);
    pscatter3<<<nbs, 256, 0, stream>>>(src, dst, slab, runoff, n_edges, np);
    gather_apply3<<<np, 256, 0, stream>>>(slab, runoff, degree, winv, Fs, WtB, bias, out,
                                          n_nodes, np, nbs);
}

// Round 7
// 142.284 us; speedup vs baseline: 3.8577x; 1.0700x over previous
//
#include <hip/hip_runtime.h>

#define FEATS 64
#define PSZ   64            // nodes per partition (= one gather block)
#define MAXP  1280          // >= ceil(75000/64) = 1172
#define PSCH  2344          // edges per chunk; 2344*512 >= 1.2M
#define PEPT  10            // ceil(PSCH/256)
#define NBMAX 512           // sort blocks = runs per partition
#define CAPP  2560          // padded LDS bucket capacity (mean ~1250, >30 sigma)

typedef __attribute__((ext_vector_type(8))) short short8;   // 8 bf16 = 4 VGPRs
typedef __attribute__((ext_vector_type(4))) float floatx4;  // MFMA accumulator

static __device__ __forceinline__ unsigned short f2bf(float f) {
    const unsigned int u = __float_as_uint(f);
    return (unsigned short)((u + 0x7FFFu + ((u >> 16) & 1u)) >> 16);
}
static __device__ __forceinline__ float bflo(unsigned int u) {
    return __uint_as_float(u << 16);            // low bf16 -> fp32
}
static __device__ __forceinline__ float bfhi(unsigned int u) {
    return __uint_as_float(u & 0xFFFF0000u);    // high bf16 -> fp32
}

// ---------------------------------------------------------------------------
// K1 prep_scatter (fused): each of 512 blocks
//  (A) converts its node-slice of Fs16 = bf16(feature * rsqrt(degree[row]))
//      (block 0 also: zero row at index n_nodes, used as bucket padding; WtB),
//  (B) partition-sorts its PSCH-edge chunk in LDS (native int LDS atomics),
//      writes it back coalesced + a u16 run-offset row. ZERO global atomics.
// Record = src | dl<<17 ; prk = p | r<<11 | dl<<23.
// ---------------------------------------------------------------------------
__global__ __launch_bounds__(256) void prep_scatter(
        const float* __restrict__ degree,
        const float* __restrict__ feature,
        const float* __restrict__ Wm,
        const int* __restrict__ src,
        const int* __restrict__ dst,
        unsigned short* __restrict__ Fs16,
        unsigned short* __restrict__ WtB,
        int* __restrict__ slab,
        unsigned short* __restrict__ runoff,
        int n_nodes, int n_edges, int np, int rows_per) {
    __shared__ int cnt[MAXP];        // per-partition count, then exclusive loc
    __shared__ int ssum[256];
    __shared__ int sval[PSCH];
    const int tid = threadIdx.x;
    const int b = blockIdx.x;

    for (int i = tid; i < np; i += 256) cnt[i] = 0;

    // (A) Fs16 conversion slice — global-only, overlaps with nothing in LDS
    {
        const int r0 = b * rows_per;
        const int r1 = min(r0 + rows_per, n_nodes);
        for (int idx = r0 * FEATS + tid; idx < r1 * FEATS; idx += 256) {
            const float w = rsqrtf(degree[idx >> 6]);   // broadcast within wave
            Fs16[idx] = f2bf(feature[idx] * w);
        }
        if (b == 0) {
            if (tid < FEATS) Fs16[(size_t)n_nodes * FEATS + tid] = 0;  // zero row
            for (int idx = tid; idx < FEATS * FEATS; idx += 256) {
                const int k = idx >> 6, n = idx & 63;
                WtB[n * FEATS + k] = f2bf(Wm[idx]);     // W^T in bf16
            }
        }
    }
    __syncthreads();

    // (B) chunk sort
    const int estart = b * PSCH;
    const int eend = min(estart + PSCH, n_edges);
    const int mb = eend - estart;

    int prk[PEPT];
#pragma unroll
    for (int k = 0; k < PEPT; ++k) {
        const int e = estart + tid + (k << 8);
        prk[k] = 0;
        if (e < eend) {
            const int d = dst[e];
            const int p = d >> 6;                      // 11 bits
            const int r = atomicAdd(&cnt[p], 1);       // LDS atomic (native int)
            prk[k] = p | (r << 11) | ((d & 63) << 23); // r < 2344 (12 bits)
        }
    }
    __syncthreads();

    // block-wide exclusive scan of cnt[0..np): 5 partitions per thread
    int my[5];
    int psum = 0;
    const int p0 = tid * 5;
#pragma unroll
    for (int j = 0; j < 5; ++j) {
        const int p = p0 + j;
        my[j] = psum;
        if (p < np) psum += cnt[p];
    }
    ssum[tid] = psum;
    __syncthreads();
#pragma unroll
    for (int o = 1; o < 256; o <<= 1) {
        const int v = (tid >= o) ? ssum[tid - o] : 0;
        __syncthreads();
        ssum[tid] += v;
        __syncthreads();
    }
    const int tbase = ssum[tid] - psum;
#pragma unroll
    for (int j = 0; j < 5; ++j) {
        const int p = p0 + j;
        if (p < np) cnt[p] = tbase + my[j];            // cnt becomes loc
    }
    __syncthreads();

#pragma unroll
    for (int k = 0; k < PEPT; ++k) {
        const int e = estart + tid + (k << 8);
        if (e < eend) {
            const int pr = prk[k];
            const int p = pr & 2047;
            const int r = (pr >> 11) & 4095;
            const int dl = (pr >> 23) & 63;
            sval[cnt[p] + r] = (src[e] & 0x1FFFF) | (dl << 17);
        }
    }
    __syncthreads();

    int* so = slab + estart;
    for (int i = tid; i < mb; i += 256) so[i] = sval[i];   // coalesced
    unsigned short* ro = runoff + (size_t)b * (np + 1);
    for (int i = tid; i <= np; i += 256)
        ro[i] = (unsigned short)((i < np) ? cnt[i] : mb);
}

// ---------------------------------------------------------------------------
// K2 gather_apply4: block = partition p. NO fp32 LDS atomics.
//  (a) per-node 8-aligned bucket offsets from degree (wave-0 shuffle scan),
//      swinv = rsqrt(degree) inline,
//  (b) prefill ledges with the zero-row index (pad slots stay harmless),
//      bucket records by node from the sorted slab runs (int LDS atomics),
//  (c) register accumulation, 2 edges per wave-load: lanes 0-31 edge j,
//      lanes 32-63 edge j+1, each lane loads a uint (2 bf16 cols); no tail,
//      no predication; lane^32 shuffle folds the half-wave partials,
//  (d) MFMA epilogue: bf16 A-tile (stride 72), 8x mfma_16x16x32_bf16,
//      out = swinv[n]*(A@W)+b.
// ---------------------------------------------------------------------------
__global__ __launch_bounds__(256) void gather_apply4(
        const int* __restrict__ slab,
        const unsigned short* __restrict__ runoff,
        const float* __restrict__ degree,
        const unsigned short* __restrict__ Fs16,
        const unsigned short* __restrict__ WtB,
        const float* __restrict__ bias,
        float* __restrict__ out,
        int n_nodes, int np, int nbs) {
    __shared__ __align__(16) int ledges[CAPP];                // 10 KB
    __shared__ __align__(16) unsigned short saggb[PSZ * 72];  // 9.2 KB bf16 A-tile
    __shared__ int boffA[PSZ + 1];
    __shared__ int bcnt[PSZ];
    __shared__ int bcur[PSZ];
    __shared__ float swinv[PSZ];

    const int tid = threadIdx.x;
    const int lane = tid & 63;
    const int wv = tid >> 6;
    const int p = blockIdx.x;
    const int n0 = p * PSZ;
    const int nn = min(PSZ, n_nodes - n0);

    if (tid < PSZ) bcur[tid] = 0;
    if (wv == 0) {   // wave-0: swinv + shuffle scan of 8-padded counts
        const float dg = (lane < nn) ? degree[n0 + lane] : 1.0f;
        swinv[lane] = rsqrtf(dg);
        const int c = (lane < nn) ? ((int)(dg + 0.5f) - 1) : 0;
        const int cp = (c + 7) & ~7;
        int x = cp;
#pragma unroll
        for (int off = 1; off < 64; off <<= 1) {
            const int v = __shfl_up(x, off);
            if (lane >= off) x += v;
        }
        if (lane == 0) boffA[0] = 0;
        boffA[lane + 1] = x;
        bcnt[lane] = c;
    }
    __syncthreads();
    const int mpad = boffA[PSZ];
    const unsigned int* FsU = (const unsigned int*)Fs16;   // 32 uints per row

    if (mpad <= CAPP) {
        // (b) prefill pad slots with zero-row index, then bucket
        for (int i = tid; i < mpad; i += 256) ledges[i] = n_nodes;
        __syncthreads();
        for (int rr = tid; rr < nbs; rr += 256) {
            const unsigned short* ro = runoff + (size_t)rr * (np + 1);
            const int st = ro[p];
            const int en = ro[p + 1];
            const int* g = slab + (size_t)rr * PSCH;
            for (int q = st; q < en; ++q) {
                const int rec = g[q];
                const int dl = (rec >> 17) & 63;
                const int pos = boffA[dl] + atomicAdd(&bcur[dl], 1);
                ledges[pos] = rec & 0x1FFFF;
            }
        }
        __syncthreads();

        // (c) 2 edges per wave-load, 4 loads per 8-edge step, zero-pad = no tail
        const int half = lane >> 5;
        const int c32 = lane & 31;
        for (int n = wv; n < PSZ; n += 4) {
            const int st = boffA[n];
            const int en8 = boffA[n + 1];
            float ax0 = 0.f, ay0 = 0.f, ax1 = 0.f, ay1 = 0.f;
            float ax2 = 0.f, ay2 = 0.f, ax3 = 0.f, ay3 = 0.f;
#pragma unroll 2
            for (int j = st; j < en8; j += 8) {
                const int r0 = ledges[j + 0 + half];
                const int r1 = ledges[j + 2 + half];
                const int r2 = ledges[j + 4 + half];
                const int r3 = ledges[j + 6 + half];
                const unsigned int u0 = FsU[((size_t)r0 << 5) + c32];
                const unsigned int u1 = FsU[((size_t)r1 << 5) + c32];
                const unsigned int u2 = FsU[((size_t)r2 << 5) + c32];
                const unsigned int u3 = FsU[((size_t)r3 << 5) + c32];
                ax0 += bflo(u0); ay0 += bfhi(u0);
                ax1 += bflo(u1); ay1 += bfhi(u1);
                ax2 += bflo(u2); ay2 += bfhi(u2);
                ax3 += bflo(u3); ay3 += bfhi(u3);
            }
            float ax = (ax0 + ax1) + (ax2 + ax3);
            float ay = (ay0 + ay1) + (ay2 + ay3);
            ax += __shfl(ax, lane ^ 32);               // fold half-waves
            ay += __shfl(ay, lane ^ 32);
            if (half == 0) {
                const unsigned int pk =
                    (unsigned int)f2bf(ax) | ((unsigned int)f2bf(ay) << 16);
                ((unsigned int*)saggb)[n * 36 + c32] = pk;   // stride 72 ushorts
            }
        }
    } else {
        // statistically-unreachable overflow: per-node scan of all runs
        __syncthreads();
        __syncthreads();
        for (int n = wv; n < PSZ; n += 4) {
            float acc = 0.f;
            for (int t = 0; t < nbs; ++t) {
                const unsigned short* ro = runoff + (size_t)t * (np + 1);
                const int gb = t * PSCH;
                const int e0 = ro[p + 1];
                for (int i = ro[p]; i < e0; ++i) {
                    const int rec = slab[gb + i];
                    if (((rec >> 17) & 63) == n) {
                        const unsigned int us =
                            Fs16[((size_t)(rec & 0x1FFFF) << 6) + lane];
                        acc += __uint_as_float(us << 16);
                    }
                }
            }
            saggb[n * 72 + lane] = f2bf(acc);
        }
    }
    __syncthreads();

    // (d) 64x64x64 GEMM: wave wv owns m-tile wv; 4 n-tiles x 2 k-steps = 8 MFMA
    const int col = lane & 15;
    const int quad = lane >> 4;
    floatx4 acc[4] = {};
#pragma unroll
    for (int kt = 0; kt < 2; ++kt) {
        const short8 af = *(const short8*)(saggb + (wv * 16 + col) * 72 + kt * 32 + quad * 8);
#pragma unroll
        for (int nt = 0; nt < 4; ++nt) {
            const short8 bf = *(const short8*)((const short*)WtB + (nt * 16 + col) * FEATS + kt * 32 + quad * 8);
            acc[nt] = __builtin_amdgcn_mfma_f32_16x16x32_bf16(af, bf, acc[nt], 0, 0, 0);
        }
    }
#pragma unroll
    for (int nt = 0; nt < 4; ++nt) {
        const float bv = bias[nt * 16 + col];
#pragma unroll
        for (int r = 0; r < 4; ++r) {
            const int row = wv * 16 + quad * 4 + r;      // D: col=lane&15, row=quad*4+reg
            if (row < nn)
                out[(size_t)(n0 + row) * FEATS + nt * 16 + col] = swinv[row] * acc[nt][r] + bv;
        }
    }
}

static inline size_t align256(size_t x) { return (x + 255) & ~(size_t)255; }

extern "C" void kernel_launch(void* const* d_in, const int* in_sizes, int n_in,
                              void* d_out, int out_size, void* d_ws, size_t ws_size,
                              hipStream_t stream) {
    const float* feature = (const float*)d_in[0];
    const float* degree  = (const float*)d_in[1];
    const int*   src     = (const int*)d_in[2];
    const int*   dst     = (const int*)d_in[3];
    const float* Wm      = (const float*)d_in[4];
    const float* bias    = (const float*)d_in[5];
    float* out = (float*)d_out;

    const int n_nodes = in_sizes[1];
    const int n_edges = in_sizes[2];
    const int np = (n_nodes + PSZ - 1) / PSZ;           // 1172
    const int nbs = (n_edges + PSCH - 1) / PSCH;        // 512
    const int rows_per = (n_nodes + nbs - 1) / nbs;     // 147

    // workspace (~15.7 MB), every byte read is rewritten each launch
    char* ws = (char*)d_ws;
    unsigned short* Fs16 = (unsigned short*)ws; ws += align256(((size_t)n_nodes + 1) * FEATS * 2);
    unsigned short* WtB  = (unsigned short*)ws; ws += align256((size_t)FEATS * FEATS * 2);
    int* slab = (int*)ws;                       ws += align256((size_t)nbs * PSCH * 4);
    unsigned short* runoff = (unsigned short*)ws; ws += align256((size_t)nbs * (np + 1) * 2);

    prep_scatter<<<nbs, 256, 0, stream>>>(degree, feature, Wm, src, dst,
                                          Fs16, WtB, slab, runoff,
                                          n_nodes, n_edges, np, rows_per);
    gather_apply4<<<np, 256, 0, stream>>>(slab, runoff, degree, Fs16, WtB, bias, out,
                                          n_nodes, np, nbs);
}

// Round 8
// 133.867 us; speedup vs baseline: 4.1003x; 1.0629x over previous
//
#include <hip/hip_runtime.h>

#define FEATS 64
#define PSZ   64            // nodes per partition (= one gather block)
#define MAXP  1280          // >= ceil(75000/64) = 1172
#define PSCH  2344          // edges per chunk; 2344*512 >= 1.2M
#define SPT   512           // prep_scatter threads per block
#define PEPT  5             // ceil(PSCH/SPT)
#define NBMAX 512           // sort blocks = runs per partition
#define CAPP  2560          // padded LDS bucket capacity (mean ~1250, >30 sigma)

typedef __attribute__((ext_vector_type(8))) short short8;   // 8 bf16 = 4 VGPRs
typedef __attribute__((ext_vector_type(4))) float floatx4;  // MFMA accumulator

static __device__ __forceinline__ unsigned short f2bf(float f) {
    const unsigned int u = __float_as_uint(f);
    return (unsigned short)((u + 0x7FFFu + ((u >> 16) & 1u)) >> 16);
}
static __device__ __forceinline__ float bflo(unsigned int u) {
    return __uint_as_float(u << 16);            // low bf16 -> fp32
}
static __device__ __forceinline__ float bfhi(unsigned int u) {
    return __uint_as_float(u & 0xFFFF0000u);    // high bf16 -> fp32
}

// ---------------------------------------------------------------------------
// K1 prep_scatter (fused, 512 threads for 16 waves/CU): each of 512 blocks
//  (A) converts its node-slice of Fs16 = bf16(feature * rsqrt(degree[row]))
//      (block 0 also: zero pad-row at index n_nodes; WtB = W^T bf16),
//  (B) partition-sorts its PSCH-edge chunk in LDS (native int LDS atomics),
//      writes it back coalesced + a u16 run-offset row. ZERO global atomics.
// Record = src | dl<<17 ; prk = p | r<<11 | dl<<23.
// ---------------------------------------------------------------------------
__global__ __launch_bounds__(SPT) void prep_scatter(
        const float* __restrict__ degree,
        const float* __restrict__ feature,
        const float* __restrict__ Wm,
        const int* __restrict__ src,
        const int* __restrict__ dst,
        unsigned short* __restrict__ Fs16,
        unsigned short* __restrict__ WtB,
        int* __restrict__ slab,
        unsigned short* __restrict__ runoff,
        int n_nodes, int n_edges, int np, int rows_per) {
    __shared__ int cnt[MAXP];        // per-partition count, then exclusive loc
    __shared__ int ssum[SPT];
    __shared__ int sval[PSCH];
    const int tid = threadIdx.x;
    const int b = blockIdx.x;

    for (int i = tid; i < np; i += SPT) cnt[i] = 0;

    // (A) Fs16 conversion slice — global-only traffic, overlaps the sort setup
    {
        const int r0 = b * rows_per;
        const int r1 = min(r0 + rows_per, n_nodes);
        for (int idx = r0 * FEATS + tid; idx < r1 * FEATS; idx += SPT) {
            const float w = rsqrtf(degree[idx >> 6]);
            Fs16[idx] = f2bf(feature[idx] * w);
        }
        if (b == 0) {
            if (tid < FEATS) Fs16[(size_t)n_nodes * FEATS + tid] = 0;  // zero row
            for (int idx = tid; idx < FEATS * FEATS; idx += SPT) {
                const int k = idx >> 6, n = idx & 63;
                WtB[n * FEATS + k] = f2bf(Wm[idx]);     // W^T in bf16
            }
        }
    }
    __syncthreads();

    // (B) chunk sort
    const int estart = b * PSCH;
    const int eend = min(estart + PSCH, n_edges);
    const int mb = eend - estart;

    int prk[PEPT];
#pragma unroll
    for (int k = 0; k < PEPT; ++k) {
        const int e = estart + tid + k * SPT;
        prk[k] = 0;
        if (e < eend) {
            const int d = dst[e];
            const int p = d >> 6;                      // 11 bits
            const int r = atomicAdd(&cnt[p], 1);       // LDS atomic (native int)
            prk[k] = p | (r << 11) | ((d & 63) << 23); // r < 2344 (12 bits)
        }
    }
    __syncthreads();

    // block-wide exclusive scan of cnt[0..np): 3 partitions per thread
    int my[3];
    int psum = 0;
    const int p0 = tid * 3;
#pragma unroll
    for (int j = 0; j < 3; ++j) {
        const int p = p0 + j;
        my[j] = psum;
        if (p < np) psum += cnt[p];
    }
    ssum[tid] = psum;
    __syncthreads();
#pragma unroll
    for (int o = 1; o < SPT; o <<= 1) {
        const int v = (tid >= o) ? ssum[tid - o] : 0;
        __syncthreads();
        ssum[tid] += v;
        __syncthreads();
    }
    const int tbase = ssum[tid] - psum;
#pragma unroll
    for (int j = 0; j < 3; ++j) {
        const int p = p0 + j;
        if (p < np) cnt[p] = tbase + my[j];            // cnt becomes loc
    }
    __syncthreads();

#pragma unroll
    for (int k = 0; k < PEPT; ++k) {
        const int e = estart + tid + k * SPT;
        if (e < eend) {
            const int pr = prk[k];
            const int p = pr & 2047;
            const int r = (pr >> 11) & 4095;
            const int dl = (pr >> 23) & 63;
            sval[cnt[p] + r] = (src[e] & 0x1FFFF) | (dl << 17);
        }
    }
    __syncthreads();

    int* so = slab + estart;
    for (int i = tid; i < mb; i += SPT) so[i] = sval[i];   // coalesced
    unsigned short* ro = runoff + (size_t)b * (np + 1);
    for (int i = tid; i <= np; i += SPT)
        ro[i] = (unsigned short)((i < np) ? cnt[i] : mb);
}

// ---------------------------------------------------------------------------
// K2 gather_apply5: block = partition p. NO fp32 LDS atomics.
//  (a) per-node 8-aligned bucket offsets from degree (wave-0 shuffle scan),
//  (b) prefill ledges with zero-row index (pad slots harmless), bucket
//      records by node from the sorted slab runs (int LDS atomics only),
//  (c) register accumulation, 4 edges per wave-load: quarter q4 = lane>>4
//      takes edge j+q4, each lane loads uint2 (4 bf16 cols); zero-pad = no
//      tail; two shuffles (lane^16, lane^32) fold quarter partials,
//  (d) MFMA epilogue: bf16 A-tile (stride 72), 8x mfma_16x16x32_bf16,
//      out = swinv[n]*(A@W)+b.
// ---------------------------------------------------------------------------
__global__ __launch_bounds__(256) void gather_apply5(
        const int* __restrict__ slab,
        const unsigned short* __restrict__ runoff,
        const float* __restrict__ degree,
        const unsigned short* __restrict__ Fs16,
        const unsigned short* __restrict__ WtB,
        const float* __restrict__ bias,
        float* __restrict__ out,
        int n_nodes, int np, int nbs) {
    __shared__ __align__(16) int ledges[CAPP];                // 10 KB
    __shared__ __align__(16) unsigned short saggb[PSZ * 72];  // 9.2 KB bf16 A-tile
    __shared__ int boffA[PSZ + 1];
    __shared__ int bcnt[PSZ];
    __shared__ int bcur[PSZ];
    __shared__ float swinv[PSZ];

    const int tid = threadIdx.x;
    const int lane = tid & 63;
    const int wv = tid >> 6;
    const int p = blockIdx.x;
    const int n0 = p * PSZ;
    const int nn = min(PSZ, n_nodes - n0);

    if (tid < PSZ) bcur[tid] = 0;
    if (wv == 0) {   // wave-0: swinv + shuffle scan of 8-padded counts
        const float dg = (lane < nn) ? degree[n0 + lane] : 1.0f;
        swinv[lane] = rsqrtf(dg);
        const int c = (lane < nn) ? ((int)(dg + 0.5f) - 1) : 0;
        const int cp = (c + 7) & ~7;
        int x = cp;
#pragma unroll
        for (int off = 1; off < 64; off <<= 1) {
            const int v = __shfl_up(x, off);
            if (lane >= off) x += v;
        }
        if (lane == 0) boffA[0] = 0;
        boffA[lane + 1] = x;
        bcnt[lane] = c;
    }
    __syncthreads();
    const int mpad = boffA[PSZ];
    const uint2* FsU2 = (const uint2*)Fs16;   // 16 uint2 per 128B row

    if (mpad <= CAPP) {
        // (b) prefill pad slots with zero-row index, then bucket
        for (int i = tid; i < mpad; i += 256) ledges[i] = n_nodes;
        __syncthreads();
        for (int rr = tid; rr < nbs; rr += 256) {
            const unsigned short* ro = runoff + (size_t)rr * (np + 1);
            const int st = ro[p];
            const int en = ro[p + 1];
            const int* g = slab + (size_t)rr * PSCH;
            for (int q = st; q < en; ++q) {
                const int rec = g[q];
                const int dl = (rec >> 17) & 63;
                const int pos = boffA[dl] + atomicAdd(&bcur[dl], 1);
                ledges[pos] = rec & 0x1FFFF;
            }
        }
        __syncthreads();

        // (c) 4 edges per wave-load (uint2/lane), 2 loads per 8-edge step
        const int q4 = lane >> 4;                  // quarter: edge within group
        const int c16 = lane & 15;                 // 4 cols per lane
        for (int n = wv; n < PSZ; n += 4) {
            const int st = boffA[n];
            const int en8 = boffA[n + 1];
            float a0 = 0.f, a1 = 0.f, a2 = 0.f, a3 = 0.f;
            float c0 = 0.f, c1 = 0.f, c2 = 0.f, c3 = 0.f;
#pragma unroll 2
            for (int j = st; j < en8; j += 8) {
                const int r0 = ledges[j + q4];
                const int r1 = ledges[j + 4 + q4];
                const uint2 u0 = FsU2[((size_t)r0 << 4) + c16];
                const uint2 u1 = FsU2[((size_t)r1 << 4) + c16];
                a0 += bflo(u0.x); a1 += bfhi(u0.x);
                a2 += bflo(u0.y); a3 += bfhi(u0.y);
                c0 += bflo(u1.x); c1 += bfhi(u1.x);
                c2 += bflo(u1.y); c3 += bfhi(u1.y);
            }
            float v0 = a0 + c0, v1 = a1 + c1, v2 = a2 + c2, v3 = a3 + c3;
            v0 += __shfl(v0, lane ^ 16); v0 += __shfl(v0, lane ^ 32);
            v1 += __shfl(v1, lane ^ 16); v1 += __shfl(v1, lane ^ 32);
            v2 += __shfl(v2, lane ^ 16); v2 += __shfl(v2, lane ^ 32);
            v3 += __shfl(v3, lane ^ 16); v3 += __shfl(v3, lane ^ 32);
            if (q4 == 0) {   // lanes 0-15 hold cols c16*4 .. c16*4+3
                const unsigned int pk0 =
                    (unsigned int)f2bf(v0) | ((unsigned int)f2bf(v1) << 16);
                const unsigned int pk1 =
                    (unsigned int)f2bf(v2) | ((unsigned int)f2bf(v3) << 16);
                uint2* dp = (uint2*)(saggb + n * 72 + c16 * 4);
                *dp = make_uint2(pk0, pk1);
            }
        }
    } else {
        // statistically-unreachable overflow: per-node scan of all runs
        __syncthreads();
        __syncthreads();
        for (int n = wv; n < PSZ; n += 4) {
            float acc = 0.f;
            for (int t = 0; t < nbs; ++t) {
                const unsigned short* ro = runoff + (size_t)t * (np + 1);
                const int gb = t * PSCH;
                const int e0 = ro[p + 1];
                for (int i = ro[p]; i < e0; ++i) {
                    const int rec = slab[gb + i];
                    if (((rec >> 17) & 63) == n) {
                        const unsigned int us =
                            Fs16[((size_t)(rec & 0x1FFFF) << 6) + lane];
                        acc += __uint_as_float(us << 16);
                    }
                }
            }
            saggb[n * 72 + lane] = f2bf(acc);
        }
    }
    __syncthreads();

    // (d) 64x64x64 GEMM: wave wv owns m-tile wv; 4 n-tiles x 2 k-steps = 8 MFMA
    const int col = lane & 15;
    const int quad = lane >> 4;
    floatx4 acc[4] = {};
#pragma unroll
    for (int kt = 0; kt < 2; ++kt) {
        const short8 af = *(const short8*)(saggb + (wv * 16 + col) * 72 + kt * 32 + quad * 8);
#pragma unroll
        for (int nt = 0; nt < 4; ++nt) {
            const short8 bf = *(const short8*)((const short*)WtB + (nt * 16 + col) * FEATS + kt * 32 + quad * 8);
            acc[nt] = __builtin_amdgcn_mfma_f32_16x16x32_bf16(af, bf, acc[nt], 0, 0, 0);
        }
    }
#pragma unroll
    for (int nt = 0; nt < 4; ++nt) {
        const float bv = bias[nt * 16 + col];
#pragma unroll
        for (int r = 0; r < 4; ++r) {
            const int row = wv * 16 + quad * 4 + r;      // D: col=lane&15, row=quad*4+reg
            if (row < nn)
                out[(size_t)(n0 + row) * FEATS + nt * 16 + col] = swinv[row] * acc[nt][r] + bv;
        }
    }
}

static inline size_t align256(size_t x) { return (x + 255) & ~(size_t)255; }

extern "C" void kernel_launch(void* const* d_in, const int* in_sizes, int n_in,
                              void* d_out, int out_size, void* d_ws, size_t ws_size,
                              hipStream_t stream) {
    const float* feature = (const float*)d_in[0];
    const float* degree  = (const float*)d_in[1];
    const int*   src     = (const int*)d_in[2];
    const int*   dst     = (const int*)d_in[3];
    const float* Wm      = (const float*)d_in[4];
    const float* bias    = (const float*)d_in[5];
    float* out = (float*)d_out;

    const int n_nodes = in_sizes[1];
    const int n_edges = in_sizes[2];
    const int np = (n_nodes + PSZ - 1) / PSZ;           // 1172
    const int nbs = (n_edges + PSCH - 1) / PSCH;        // 512
    const int rows_per = (n_nodes + nbs - 1) / nbs;     // 147

    // workspace (~15.7 MB), every byte read is rewritten each launch
    char* ws = (char*)d_ws;
    unsigned short* Fs16 = (unsigned short*)ws; ws += align256(((size_t)n_nodes + 1) * FEATS * 2);
    unsigned short* WtB  = (unsigned short*)ws; ws += align256((size_t)FEATS * FEATS * 2);
    int* slab = (int*)ws;                       ws += align256((size_t)nbs * PSCH * 4);
    unsigned short* runoff = (unsigned short*)ws; ws += align256((size_t)nbs * (np + 1) * 2);

    prep_scatter<<<nbs, SPT, 0, stream>>>(degree, feature, Wm, src, dst,
                                          Fs16, WtB, slab, runoff,
                                          n_nodes, n_edges, np, rows_per);
    gather_apply5<<<np, 256, 0, stream>>>(slab, runoff, degree, Fs16, WtB, bias, out,
                                          n_nodes, np, nbs);
}